// Round 3
// baseline (401.116 us; speedup 1.0000x reference)
//
#include <hip/hip_runtime.h>
#include <hip/hip_bf16.h>
#include <math.h>

#define NTOK 100352          // 32*56*56
typedef __attribute__((ext_vector_type(8))) short short8_t;
typedef __attribute__((ext_vector_type(4))) float f32x4;

union I4S8 { int4 i; short h[8]; short8_t v; };

__device__ __forceinline__ short f2bf(float f) {
    union { float f; unsigned u; } x; x.f = f;
    unsigned r = x.u + 0x7FFFu + ((x.u >> 16) & 1u);
    return (short)(r >> 16);
}
__device__ __forceinline__ float bf2f(short s) {
    union { unsigned u; float f; } x; x.u = ((unsigned)(unsigned short)s) << 16;
    return x.f;
}

// async global->LDS, 16B per lane, wave-uniform LDS base + lane*16
#define GLDS16(gsrc, ldst) __builtin_amdgcn_global_load_lds( \
    (const __attribute__((address_space(1))) unsigned int*)(gsrc), \
    (__attribute__((address_space(3))) unsigned int*)(ldst), 16, 0, 0)

// ---------------- weight prep: f32 [K][N] -> bf16 [N][K] ----------------
__global__ void prep_weights(const float* __restrict__ qkv_w, const float* __restrict__ proj_w,
                             const float* __restrict__ fc1_w, const float* __restrict__ fc2_w,
                             short* __restrict__ wt) {
    int idx = blockIdx.x * 256 + threadIdx.x;
    const float* src; int K, N, base;
    if (idx < 49152)       { src = qkv_w;  K = 128; N = 384; base = 0; }
    else if (idx < 65536)  { src = proj_w; K = 128; N = 128; base = 49152; }
    else if (idx < 131072) { src = fc1_w;  K = 128; N = 512; base = 65536; }
    else                   { src = fc2_w;  K = 512; N = 128; base = 131072; }
    int local = idx - base;
    int n = local / K, k = local - n * K;
    wt[idx] = f2bf(src[k * N + n]);
}

// ---------------- LayerNorm (f32 in) -> bf16 out ----------------
__global__ __launch_bounds__(256) void ln_kernel(const float* __restrict__ in,
                                                 const float* __restrict__ g,
                                                 const float* __restrict__ b,
                                                 short* __restrict__ out) {
    int token = blockIdx.x * 4 + (threadIdx.x >> 6);
    int lane = threadIdx.x & 63;
    const float2 v = *reinterpret_cast<const float2*>(in + (size_t)token * 128 + lane * 2);
    float s = v.x + v.y;
    float sq = v.x * v.x + v.y * v.y;
    #pragma unroll
    for (int m = 32; m >= 1; m >>= 1) {
        s  += __shfl_xor(s, m);
        sq += __shfl_xor(sq, m);
    }
    float mean = s * (1.0f / 128.0f);
    float var = sq * (1.0f / 128.0f) - mean * mean;
    float rstd = rsqrtf(var + 1e-5f);
    float2 gg = *reinterpret_cast<const float2*>(g + lane * 2);
    float2 bb = *reinterpret_cast<const float2*>(b + lane * 2);
    float o0 = (v.x - mean) * rstd * gg.x + bb.x;
    float o1 = (v.y - mean) * rstd * gg.y + bb.y;
    unsigned pack = ((unsigned)(unsigned short)f2bf(o0)) |
                    (((unsigned)(unsigned short)f2bf(o1)) << 16);
    *reinterpret_cast<unsigned*>(out + (size_t)token * 128 + lane * 2) = pack;
}

// ---------------- GEMM: A bf16 [M][K] @ BT bf16 [N][K], 128x128 tile ----------------
// A-tile: global_load_lds (16B) into linear LDS with XOR-swizzled global source;
// B-frags: straight from global into registers (weights are L2-resident).
// 256 threads = 4 waves, wave (wr,wc) owns 64x64 quadrant, acc 4x4 frags.
// EPI 0: store bf16 ; 1: +bias +res -> f32 ; 2: +bias, exact GELU -> bf16
template<int EPI>
__global__ __launch_bounds__(256) void gemm_kernel(const short* __restrict__ A,
                                                   const short* __restrict__ BT,
                                                   const float* __restrict__ bias,
                                                   const float* __restrict__ res,
                                                   void* __restrict__ out,
                                                   int N, int K) {
    __shared__ short As[128 * 64];      // 16 KB, linear [row][64], swizzled segs
    const int m0 = blockIdx.x * 128;
    const int n0 = blockIdx.y * 128;
    const int tid = threadIdx.x;
    const int w = tid >> 6, lane = tid & 63;
    const int wr = w >> 1, wc = w & 1;
    const int r = lane & 15, g = lane >> 4;

    f32x4 acc[4][4];
    #pragma unroll
    for (int i = 0; i < 4; ++i)
        #pragma unroll
        for (int j = 0; j < 4; ++j) acc[i][j] = (f32x4){0.f, 0.f, 0.f, 0.f};

    // staging geometry (per wave): 4 issues x (8 rows x 8 segs of 16B)
    const int srow_in_issue = lane >> 3;         // 0..7
    const int sseg_lane = lane & 7;              // 0..7

    for (int kc = 0; kc < K; kc += 64) {
        // ---- stage A tile: rows w*32 .. w*32+31 ----
        #pragma unroll
        for (int t = 0; t < 4; ++t) {
            int row = w * 32 + t * 8 + srow_in_issue;
            int sseg = sseg_lane ^ (row & 7);
            const short* gsrc = A + (size_t)(m0 + row) * K + kc + sseg * 8;
            GLDS16(gsrc, &As[(w * 32 + t * 8) * 64]);
        }
        // ---- B frags from global (L2-hot weights) ----
        short8_t bfr[2][4];
        #pragma unroll
        for (int ks = 0; ks < 2; ++ks)
            #pragma unroll
            for (int nf = 0; nf < 4; ++nf) {
                int brow = n0 + wc * 64 + nf * 16 + r;
                bfr[ks][nf] = *reinterpret_cast<const short8_t*>(
                    BT + (size_t)brow * K + kc + ks * 32 + g * 8);
            }
        __syncthreads();   // drains vmcnt (global_load_lds) per barrier semantics
        #pragma unroll
        for (int ks = 0; ks < 2; ++ks) {
            #pragma unroll
            for (int mf = 0; mf < 4; ++mf) {
                int arow = wr * 64 + mf * 16 + r;
                int s0 = (ks * 4 + g) ^ (arow & 7);
                short8_t af = *reinterpret_cast<const short8_t*>(&As[arow * 64 + s0 * 8]);
                #pragma unroll
                for (int nf = 0; nf < 4; ++nf)
                    acc[mf][nf] = __builtin_amdgcn_mfma_f32_16x16x32_bf16(af, bfr[ks][nf], acc[mf][nf], 0, 0, 0);
            }
        }
        __syncthreads();
    }

    #pragma unroll
    for (int nf = 0; nf < 4; ++nf) {
        int col = n0 + wc * 64 + nf * 16 + r;
        float bv = (EPI != 0) ? bias[col] : 0.f;
        #pragma unroll
        for (int mf = 0; mf < 4; ++mf) {
            #pragma unroll
            for (int j = 0; j < 4; ++j) {
                int row = m0 + wr * 64 + mf * 16 + g * 4 + j;
                float v = acc[mf][nf][j];
                if (EPI == 0) {
                    ((short*)out)[(size_t)row * N + col] = f2bf(v);
                } else if (EPI == 1) {
                    ((float*)out)[(size_t)row * N + col] = v + bv + res[(size_t)row * N + col];
                } else {
                    float t = v + bv;
                    float ge = 0.5f * t * (1.0f + erff(t * 0.70710678118654752f));
                    ((short*)out)[(size_t)row * N + col] = f2bf(ge);
                }
            }
        }
    }
}

// ---------------- fused window attention + LEPE (wave-parallel softmax) ----------------
// grid (896, 2, 2): x = window (b*28 + w), y = head, z = type (0: 56x2, 1: 2x56)
__global__ __launch_bounds__(256) void attn_kernel(const short* __restrict__ qkv,
                                                   const float* __restrict__ cw0,
                                                   const float* __restrict__ cb0,
                                                   const float* __restrict__ cw1,
                                                   const float* __restrict__ cb1,
                                                   short* __restrict__ attout) {
    __shared__ short P[112][120];   // normalized probs, bf16
    __shared__ short vT[32][120];   // V transposed: vT[d][tok]

    const int win = blockIdx.x;
    const int head = blockIdx.y;
    const int type = blockIdx.z;
    const int b = win / 28;
    const int wdx = win - b * 28;
    const int tid = threadIdx.x;
    const int wv = tid >> 6, lane = tid & 63;
    const int r = lane & 15, g = lane >> 4;
    const int chb = type * 64 + head * 32;
    const float* cw = type ? cw1 : cw0;
    const float* cb = type ? cb1 : cb0;

    auto rowof = [&](int t) -> int {
        int l;
        if (type == 0) { int hs = t >> 1, wsp = t & 1; l = hs * 56 + wdx * 2 + wsp; }
        else           { int hs = (t >= 56) ? 1 : 0, wsp = t - hs * 56; l = (wdx * 2 + hs) * 56 + wsp; }
        return b * 3136 + l;
    };

    // stage V transposed: vT[d][tok]
    for (int i = tid; i < 448; i += 256) {
        int tt = i >> 2, seg = i & 3;
        int roww = rowof(tt);
        I4S8 u; u.i = *reinterpret_cast<const int4*>(qkv + (size_t)roww * 384 + 256 + chb + seg * 8);
        #pragma unroll
        for (int j = 0; j < 8; ++j) vT[seg * 8 + j][tt] = u.h[j];
    }

    // K-frags (B-operand) in registers, shared across this wave's m-tiles
    short8_t kf[7];
    #pragma unroll
    for (int nt = 0; nt < 7; ++nt) {
        int roww = rowof(nt * 16 + r);
        kf[nt] = *reinterpret_cast<const short8_t*>(qkv + (size_t)roww * 384 + 128 + chb + g * 8);
    }

    // QK^T into registers: sa[t][nt], t indexes this wave's m-tiles {wv, wv+4}
    f32x4 sa[2][7];
    #pragma unroll
    for (int t = 0; t < 2; ++t)
        #pragma unroll
        for (int nt = 0; nt < 7; ++nt)
            sa[t][nt] = (f32x4){0.f, 0.f, 0.f, 0.f};

    #pragma unroll
    for (int t = 0; t < 2; ++t) {
        int mt = wv + 4 * t;
        if (mt < 7) {
            int roww = rowof(mt * 16 + r);
            short8_t af = *reinterpret_cast<const short8_t*>(qkv + (size_t)roww * 384 + chb + g * 8);
            #pragma unroll
            for (int nt = 0; nt < 7; ++nt)
                sa[t][nt] = __builtin_amdgcn_mfma_f32_16x16x32_bf16(af, kf[nt], sa[t][nt], 0, 0, 0);
        }
    }

    // in-register softmax; rows of frag = g*4+j, cols nt*16+r (16-lane group)
    const float scale = 0.17677669529663687f; // 1/sqrt(32)
    #pragma unroll
    for (int t = 0; t < 2; ++t) {
        int mt = wv + 4 * t;
        if (mt < 7) {
            #pragma unroll
            for (int j = 0; j < 4; ++j) {
                float sv[7];
                float mx = -1e30f;
                #pragma unroll
                for (int nt = 0; nt < 7; ++nt) { sv[nt] = sa[t][nt][j] * scale; mx = fmaxf(mx, sv[nt]); }
                #pragma unroll
                for (int m = 8; m >= 1; m >>= 1) mx = fmaxf(mx, __shfl_xor(mx, m));
                float sum = 0.f;
                #pragma unroll
                for (int nt = 0; nt < 7; ++nt) { sv[nt] = __expf(sv[nt] - mx); sum += sv[nt]; }
                #pragma unroll
                for (int m = 8; m >= 1; m >>= 1) sum += __shfl_xor(sum, m);
                float inv = 1.0f / sum;
                int row = mt * 16 + g * 4 + j;
                #pragma unroll
                for (int nt = 0; nt < 7; ++nt)
                    P[row][nt * 16 + r] = f2bf(sv[nt] * inv);
            }
        }
    }
    __syncthreads();

    // PV + LEPE + store. 14 output frags (7 m-tiles x 2 d-tiles); wave w: w+4t
    #pragma unroll
    for (int t = 0; t < 4; ++t) {
        int idx = wv + 4 * t;
        if (idx < 14) {
            int mt = idx >> 1, nt = idx & 1;
            int m0 = mt * 16, n0 = nt * 16;
            f32x4 acc = {0.f, 0.f, 0.f, 0.f};
            #pragma unroll
            for (int ks = 0; ks < 4; ++ks) {
                short8_t pa, vb;
                if (ks < 3 || g < 2) {
                    int k0 = ks * 32 + g * 8;
                    pa = *reinterpret_cast<const short8_t*>(&P[m0 + r][k0]);
                    vb = *reinterpret_cast<const short8_t*>(&vT[n0 + r][k0]);
                } else {
                    #pragma unroll
                    for (int j = 0; j < 8; ++j) { pa[j] = 0; vb[j] = 0; }
                }
                acc = __builtin_amdgcn_mfma_f32_16x16x32_bf16(pa, vb, acc, 0, 0, 0);
            }
            int d = n0 + r;               // hd index 0..31
            int cl = head * 32 + d;       // depthwise-conv channel 0..63
            float w9[9];
            #pragma unroll
            for (int j = 0; j < 9; ++j) w9[j] = cw[cl * 9 + j];
            float cbias = cb[cl];
            #pragma unroll
            for (int j = 0; j < 4; ++j) {
                int tok = m0 + g * 4 + j;
                float v = acc[j];
                int hs, wsp;
                if (type == 0) { hs = tok >> 1; wsp = tok & 1; }
                else           { hs = (tok >= 56) ? 1 : 0; wsp = tok - hs * 56; }
                float lp = cbias;
                #pragma unroll
                for (int ky = 0; ky < 3; ++ky) {
                    int hh = hs + ky - 1;
                    bool okh = (type == 0) ? (hh >= 0 && hh < 56) : (hh >= 0 && hh < 2);
                    #pragma unroll
                    for (int kx = 0; kx < 3; ++kx) {
                        int wwp = wsp + kx - 1;
                        bool okw = (type == 0) ? (wwp >= 0 && wwp < 2) : (wwp >= 0 && wwp < 56);
                        if (okh && okw) {
                            int tt = (type == 0) ? (hh * 2 + wwp) : (hh * 56 + wwp);
                            lp += w9[ky * 3 + kx] * bf2f(vT[d][tt]);
                        }
                    }
                }
                v += lp;
                int roww = rowof(tok);
                attout[(size_t)roww * 128 + chb + d] = f2bf(v);
            }
        }
    }
}

extern "C" void kernel_launch(void* const* d_in, const int* in_sizes, int n_in,
                              void* d_out, int out_size, void* d_ws, size_t ws_size,
                              hipStream_t stream) {
    const float* x      = (const float*)d_in[0];
    const float* n1g    = (const float*)d_in[1];
    const float* n1b    = (const float*)d_in[2];
    const float* qkv_w  = (const float*)d_in[3];
    const float* proj_w = (const float*)d_in[4];
    const float* proj_b = (const float*)d_in[5];
    const float* cw0    = (const float*)d_in[6];
    const float* cb0    = (const float*)d_in[7];
    const float* cw1    = (const float*)d_in[8];
    const float* cb1    = (const float*)d_in[9];
    const float* n2g    = (const float*)d_in[10];
    const float* n2b    = (const float*)d_in[11];
    const float* fc1_w  = (const float*)d_in[12];
    const float* fc1_b  = (const float*)d_in[13];
    const float* fc2_w  = (const float*)d_in[14];
    const float* fc2_b  = (const float*)d_in[15];
    float* out = (float*)d_out;
    char* ws = (char*)d_ws;

    // workspace layout (bytes)
    short* img   = (short*)(ws + 0);            // [100352][128] bf16  (25,690,112)
    short* qkv   = (short*)(ws + 25690112);     // [100352][384] bf16  (77,070,336)
    short* att   = (short*)(ws + 102760448);    // [100352][128] bf16  (25,690,112)
    float* xres  = (float*)(ws + 128450560);    // [100352][128] f32   (51,380,224)
    short* wT    = (short*)(ws + 179830784);    // all weights bf16 [N][K] (393,216)
    short* wqkvT  = wT;
    short* wprojT = wT + 49152;
    short* wfc1T  = wT + 65536;
    short* wfc2T  = wT + 131072;
    short* hidden = qkv;   // [100352][512] bf16, aliases qkv+att (both dead by then)
    short* y2     = img;   // LN2 output aliases img

    prep_weights<<<768, 256, 0, stream>>>(qkv_w, proj_w, fc1_w, fc2_w, wT);
    ln_kernel<<<25088, 256, 0, stream>>>(x, n1g, n1b, img);
    gemm_kernel<0><<<dim3(784, 3), 256, 0, stream>>>(img, wqkvT, nullptr, nullptr, qkv, 384, 128);
    attn_kernel<<<dim3(896, 2, 2), 256, 0, stream>>>(qkv, cw0, cb0, cw1, cb1, att);
    gemm_kernel<1><<<dim3(784, 1), 256, 0, stream>>>(att, wprojT, proj_b, x, xres, 128, 128);
    ln_kernel<<<25088, 256, 0, stream>>>(xres, n2g, n2b, y2);
    gemm_kernel<2><<<dim3(784, 4), 256, 0, stream>>>(y2, wfc1T, fc1_b, nullptr, hidden, 512, 128);
    gemm_kernel<1><<<dim3(784, 1), 256, 0, stream>>>(hidden, wfc2T, fc2_b, xres, out, 128, 512);
}

// Round 4
// 397.021 us; speedup vs baseline: 1.0103x; 1.0103x over previous
//
#include <hip/hip_runtime.h>
#include <hip/hip_bf16.h>
#include <math.h>

#define NTOK 100352          // 32*56*56
typedef __attribute__((ext_vector_type(8))) short short8_t;
typedef __attribute__((ext_vector_type(4))) float f32x4;

union I4S8 { int4 i; short h[8]; short8_t v; };

__device__ __forceinline__ short f2bf(float f) {
    union { float f; unsigned u; } x; x.f = f;
    unsigned r = x.u + 0x7FFFu + ((x.u >> 16) & 1u);
    return (short)(r >> 16);
}
__device__ __forceinline__ float bf2f(short s) {
    union { unsigned u; float f; } x; x.u = ((unsigned)(unsigned short)s) << 16;
    return x.f;
}
__device__ __forceinline__ unsigned pk2(float a, float b) {
    return ((unsigned)(unsigned short)f2bf(a)) | (((unsigned)(unsigned short)f2bf(b)) << 16);
}

// async global->LDS, 16B per lane, wave-uniform LDS base + lane*16
#define GLDS16(gsrc, ldst) __builtin_amdgcn_global_load_lds( \
    (const __attribute__((address_space(1))) unsigned int*)(gsrc), \
    (__attribute__((address_space(3))) unsigned int*)(ldst), 16, 0, 0)

// ---------------- weight prep: f32 [K][N] -> bf16 [N][K] ----------------
__global__ void prep_weights(const float* __restrict__ qkv_w, const float* __restrict__ proj_w,
                             const float* __restrict__ fc1_w, const float* __restrict__ fc2_w,
                             short* __restrict__ wt) {
    int idx = blockIdx.x * 256 + threadIdx.x;
    const float* src; int K, N, base;
    if (idx < 49152)       { src = qkv_w;  K = 128; N = 384; base = 0; }
    else if (idx < 65536)  { src = proj_w; K = 128; N = 128; base = 49152; }
    else if (idx < 131072) { src = fc1_w;  K = 128; N = 512; base = 65536; }
    else                   { src = fc2_w;  K = 512; N = 128; base = 131072; }
    int local = idx - base;
    int n = local / K, k = local - n * K;
    wt[idx] = f2bf(src[k * N + n]);
}

// ---------------- LayerNorm (f32 in) -> bf16 out ----------------
__global__ __launch_bounds__(256) void ln_kernel(const float* __restrict__ in,
                                                 const float* __restrict__ g,
                                                 const float* __restrict__ b,
                                                 short* __restrict__ out) {
    int token = blockIdx.x * 4 + (threadIdx.x >> 6);
    int lane = threadIdx.x & 63;
    const float2 v = *reinterpret_cast<const float2*>(in + (size_t)token * 128 + lane * 2);
    float s = v.x + v.y;
    float sq = v.x * v.x + v.y * v.y;
    #pragma unroll
    for (int m = 32; m >= 1; m >>= 1) {
        s  += __shfl_xor(s, m);
        sq += __shfl_xor(sq, m);
    }
    float mean = s * (1.0f / 128.0f);
    float var = sq * (1.0f / 128.0f) - mean * mean;
    float rstd = rsqrtf(var + 1e-5f);
    float2 gg = *reinterpret_cast<const float2*>(g + lane * 2);
    float2 bb = *reinterpret_cast<const float2*>(b + lane * 2);
    float o0 = (v.x - mean) * rstd * gg.x + bb.x;
    float o1 = (v.y - mean) * rstd * gg.y + bb.y;
    unsigned pack = ((unsigned)(unsigned short)f2bf(o0)) |
                    (((unsigned)(unsigned short)f2bf(o1)) << 16);
    *reinterpret_cast<unsigned*>(out + (size_t)token * 128 + lane * 2) = pack;
}

// ---------------- GEMM 128x128 tile, K=128 (one barrier), A and B via global_load_lds ----
// mfma(B,A): D[col = g*4+j][row = r] -> lane holds 4 consecutive cols of one row.
// EPI 0: pack bf16, store uint2 (qkv). EPI 1: +bias +residual -> xres f32 (float4),
//        then in-wave LN2 -> y2 bf16 (uint2). Wave owns 32 rows x 128 cols.
template<int EPI>
__global__ __launch_bounds__(256) void gemm128(const short* __restrict__ A,
                                               const short* __restrict__ BT,
                                               const float* __restrict__ bias,
                                               const float* __restrict__ resid,
                                               const float* __restrict__ g2,
                                               const float* __restrict__ b2,
                                               short* __restrict__ outb,
                                               float* __restrict__ outf,
                                               int N) {
    __shared__ short As[128 * 128];   // 32 KB, 16B-seg XOR-swizzled rows (256B each)
    __shared__ short Bs[128 * 128];   // 32 KB
    const int m0 = blockIdx.x * 128;
    const int n0 = blockIdx.y * 128;
    const int tid = threadIdx.x;
    const int w = tid >> 6, lane = tid & 63;
    const int r = lane & 15, g = lane >> 4;
    const int rr = lane >> 4, ss = lane & 15;

    // stage A and B full-K tiles; per wave 8 issues each (4 rows x 16 segs per issue)
    #pragma unroll
    for (int t = 0; t < 8; ++t) {
        int row = w * 32 + t * 4 + rr;
        int sseg = (ss & 8) | ((ss ^ row) & 7);
        GLDS16(A  + (size_t)(m0 + row) * 128 + sseg * 8, &As[(w * 32 + t * 4) * 128]);
        GLDS16(BT + (size_t)(n0 + row) * 128 + sseg * 8, &Bs[(w * 32 + t * 4) * 128]);
    }
    __syncthreads();

    f32x4 acc[2][8];
    #pragma unroll
    for (int mf = 0; mf < 2; ++mf)
        #pragma unroll
        for (int nt = 0; nt < 8; ++nt) acc[mf][nt] = (f32x4){0.f, 0.f, 0.f, 0.f};

    #pragma unroll
    for (int kf = 0; kf < 4; ++kf) {
        const int q = kf * 4 + g;
        short8_t bfr[8], af[2];
        #pragma unroll
        for (int nt = 0; nt < 8; ++nt) {
            int row = nt * 16 + r;
            int seg = (q & 8) | ((q ^ row) & 7);
            bfr[nt] = *reinterpret_cast<const short8_t*>(&Bs[row * 128 + seg * 8]);
        }
        #pragma unroll
        for (int mf = 0; mf < 2; ++mf) {
            int row = w * 32 + mf * 16 + r;
            int seg = (q & 8) | ((q ^ row) & 7);
            af[mf] = *reinterpret_cast<const short8_t*>(&As[row * 128 + seg * 8]);
        }
        #pragma unroll
        for (int mf = 0; mf < 2; ++mf)
            #pragma unroll
            for (int nt = 0; nt < 8; ++nt)
                acc[mf][nt] = __builtin_amdgcn_mfma_f32_16x16x32_bf16(bfr[nt], af[mf], acc[mf][nt], 0, 0, 0);
    }

    if (EPI == 0) {
        #pragma unroll
        for (int mf = 0; mf < 2; ++mf) {
            int row = m0 + w * 32 + mf * 16 + r;
            #pragma unroll
            for (int nt = 0; nt < 8; ++nt) {
                int col = n0 + nt * 16 + g * 4;
                uint2 p;
                p.x = pk2(acc[mf][nt][0], acc[mf][nt][1]);
                p.y = pk2(acc[mf][nt][2], acc[mf][nt][3]);
                *reinterpret_cast<uint2*>(&outb[(size_t)row * N + col]) = p;
            }
        }
    } else {
        #pragma unroll
        for (int mf = 0; mf < 2; ++mf) {
            int row = m0 + w * 32 + mf * 16 + r;
            float s = 0.f, sq = 0.f;
            #pragma unroll
            for (int nt = 0; nt < 8; ++nt) {
                int col = nt * 16 + g * 4;
                f32x4 b4 = *reinterpret_cast<const f32x4*>(&bias[col]);
                f32x4 x4 = *reinterpret_cast<const f32x4*>(&resid[(size_t)row * 128 + col]);
                #pragma unroll
                for (int j = 0; j < 4; ++j) {
                    float v = acc[mf][nt][j] + b4[j] + x4[j];
                    acc[mf][nt][j] = v;
                    s += v; sq += v * v;
                }
                *reinterpret_cast<f32x4*>(&outf[(size_t)row * 128 + col]) = acc[mf][nt];
            }
            s  += __shfl_xor(s, 16);  s  += __shfl_xor(s, 32);
            sq += __shfl_xor(sq, 16); sq += __shfl_xor(sq, 32);
            float mean = s * (1.0f / 128.0f);
            float var = sq * (1.0f / 128.0f) - mean * mean;
            float rstd = rsqrtf(var + 1e-5f);
            #pragma unroll
            for (int nt = 0; nt < 8; ++nt) {
                int col = nt * 16 + g * 4;
                f32x4 g4  = *reinterpret_cast<const f32x4*>(&g2[col]);
                f32x4 bb4 = *reinterpret_cast<const f32x4*>(&b2[col]);
                float y0 = (acc[mf][nt][0] - mean) * rstd * g4[0] + bb4[0];
                float y1 = (acc[mf][nt][1] - mean) * rstd * g4[1] + bb4[1];
                float y2v = (acc[mf][nt][2] - mean) * rstd * g4[2] + bb4[2];
                float y3 = (acc[mf][nt][3] - mean) * rstd * g4[3] + bb4[3];
                uint2 p; p.x = pk2(y0, y1); p.y = pk2(y2v, y3);
                *reinterpret_cast<uint2*>(&outb[(size_t)row * 128 + col]) = p;
            }
        }
    }
}

// ---------------- fused MLP: fc1 + GELU + fc2 + bias + residual ----------------
// 64-token tile; y2 frags in registers; hidden [64][512] bf16 in LDS (XOR-swizzled 16B segs).
__global__ __launch_bounds__(256) void mlp_kernel(const short* __restrict__ Y,
                                                  const short* __restrict__ W1T,   // [512][128]
                                                  const float* __restrict__ b1,
                                                  const short* __restrict__ W2T,   // [128][512]
                                                  const float* __restrict__ b2,
                                                  const float* __restrict__ xres,
                                                  float* __restrict__ out) {
    __shared__ short hid[64 * 512];   // 64 KB
    const int m0 = blockIdx.x * 64;
    const int tid = threadIdx.x;
    const int w = tid >> 6, lane = tid & 63;
    const int r = lane & 15, g = lane >> 4;

    // A (y2) frags: lane holds token m0+mf*16+r, k-slice g*8 (16 rows x 64B per load instr)
    short8_t af[4][4];
    #pragma unroll
    for (int mf = 0; mf < 4; ++mf)
        #pragma unroll
        for (int kf = 0; kf < 4; ++kf)
            af[mf][kf] = *reinterpret_cast<const short8_t*>(
                &Y[(size_t)(m0 + mf * 16 + r) * 128 + kf * 32 + g * 8]);

    // fc1: wave w -> hidden cols w*128..+127, two half-passes of 64 cols
    #pragma unroll
    for (int np = 0; np < 2; ++np) {
        f32x4 acc[4][4];
        #pragma unroll
        for (int mf = 0; mf < 4; ++mf)
            #pragma unroll
            for (int nt = 0; nt < 4; ++nt) acc[mf][nt] = (f32x4){0.f, 0.f, 0.f, 0.f};
        #pragma unroll
        for (int kf = 0; kf < 4; ++kf) {
            short8_t bfr[4];
            #pragma unroll
            for (int nt = 0; nt < 4; ++nt) {
                int hc = w * 128 + np * 64 + nt * 16 + r;
                bfr[nt] = *reinterpret_cast<const short8_t*>(&W1T[(size_t)hc * 128 + kf * 32 + g * 8]);
            }
            #pragma unroll
            for (int mf = 0; mf < 4; ++mf)
                #pragma unroll
                for (int nt = 0; nt < 4; ++nt)
                    acc[mf][nt] = __builtin_amdgcn_mfma_f32_16x16x32_bf16(bfr[nt], af[mf][kf], acc[mf][nt], 0, 0, 0);
        }
        // bias + GELU + pack -> LDS (8B writes, swizzled)
        #pragma unroll
        for (int mf = 0; mf < 4; ++mf) {
            int row = mf * 16 + r;
            #pragma unroll
            for (int nt = 0; nt < 4; ++nt) {
                int col = w * 128 + np * 64 + nt * 16 + g * 4;
                f32x4 b4 = *reinterpret_cast<const f32x4*>(&b1[col]);
                float h[4];
                #pragma unroll
                for (int j = 0; j < 4; ++j) {
                    float t = acc[mf][nt][j] + b4[j];
                    h[j] = 0.5f * t * (1.0f + erff(t * 0.70710678118654752f));
                }
                int s16 = col >> 3;
                int half = (col >> 2) & 1;
                int seg = (s16 & 56) | ((s16 ^ row) & 7);
                uint2 p; p.x = pk2(h[0], h[1]); p.y = pk2(h[2], h[3]);
                *reinterpret_cast<uint2*>((char*)hid + row * 1024 + seg * 16 + half * 8) = p;
            }
        }
    }
    __syncthreads();

    // fc2: wave w -> out cols w*32..+31, K=512 from LDS
    f32x4 acc2[4][2];
    #pragma unroll
    for (int tt = 0; tt < 4; ++tt)
        #pragma unroll
        for (int o = 0; o < 2; ++o) acc2[tt][o] = (f32x4){0.f, 0.f, 0.f, 0.f};
    #pragma unroll
    for (int kf = 0; kf < 16; ++kf) {
        const int q = kf * 4 + g;
        short8_t bfr2[2], hf[4];
        #pragma unroll
        for (int o = 0; o < 2; ++o) {
            int ocol = w * 32 + o * 16 + r;
            bfr2[o] = *reinterpret_cast<const short8_t*>(&W2T[(size_t)ocol * 512 + kf * 32 + g * 8]);
        }
        #pragma unroll
        for (int tt = 0; tt < 4; ++tt) {
            int row = tt * 16 + r;
            int seg = (q & 56) | ((q ^ row) & 7);
            hf[tt] = *reinterpret_cast<const short8_t*>((char*)hid + row * 1024 + seg * 16);
        }
        #pragma unroll
        for (int tt = 0; tt < 4; ++tt)
            #pragma unroll
            for (int o = 0; o < 2; ++o)
                acc2[tt][o] = __builtin_amdgcn_mfma_f32_16x16x32_bf16(bfr2[o], hf[tt], acc2[tt][o], 0, 0, 0);
    }
    #pragma unroll
    for (int tt = 0; tt < 4; ++tt) {
        int row = m0 + tt * 16 + r;
        #pragma unroll
        for (int o = 0; o < 2; ++o) {
            int col = w * 32 + o * 16 + g * 4;
            f32x4 b4 = *reinterpret_cast<const f32x4*>(&b2[col]);
            f32x4 x4 = *reinterpret_cast<const f32x4*>(&xres[(size_t)row * 128 + col]);
            f32x4 v;
            #pragma unroll
            for (int j = 0; j < 4; ++j) v[j] = acc2[tt][o][j] + b4[j] + x4[j];
            *reinterpret_cast<f32x4*>(&out[(size_t)row * 128 + col]) = v;
        }
    }
}

// ---------------- fused window attention + LEPE (wave-parallel softmax) ----------------
// grid (896, 2, 2): x = window (b*28 + w), y = head, z = type (0: 56x2, 1: 2x56)
__global__ __launch_bounds__(256) void attn_kernel(const short* __restrict__ qkv,
                                                   const float* __restrict__ cw0,
                                                   const float* __restrict__ cb0,
                                                   const float* __restrict__ cw1,
                                                   const float* __restrict__ cb1,
                                                   short* __restrict__ attout) {
    __shared__ short P[112][120];   // normalized probs, bf16
    __shared__ short vT[32][120];   // V transposed: vT[d][tok]

    const int win = blockIdx.x;
    const int head = blockIdx.y;
    const int type = blockIdx.z;
    const int b = win / 28;
    const int wdx = win - b * 28;
    const int tid = threadIdx.x;
    const int wv = tid >> 6, lane = tid & 63;
    const int r = lane & 15, g = lane >> 4;
    const int chb = type * 64 + head * 32;
    const float* cw = type ? cw1 : cw0;
    const float* cb = type ? cb1 : cb0;

    auto rowof = [&](int t) -> int {
        int l;
        if (type == 0) { int hs = t >> 1, wsp = t & 1; l = hs * 56 + wdx * 2 + wsp; }
        else           { int hs = (t >= 56) ? 1 : 0, wsp = t - hs * 56; l = (wdx * 2 + hs) * 56 + wsp; }
        return b * 3136 + l;
    };

    // stage V transposed: vT[d][tok]
    for (int i = tid; i < 448; i += 256) {
        int tt = i >> 2, seg = i & 3;
        int roww = rowof(tt);
        I4S8 u; u.i = *reinterpret_cast<const int4*>(qkv + (size_t)roww * 384 + 256 + chb + seg * 8);
        #pragma unroll
        for (int j = 0; j < 8; ++j) vT[seg * 8 + j][tt] = u.h[j];
    }

    // K-frags (B-operand) in registers, shared across this wave's m-tiles
    short8_t kf[7];
    #pragma unroll
    for (int nt = 0; nt < 7; ++nt) {
        int roww = rowof(nt * 16 + r);
        kf[nt] = *reinterpret_cast<const short8_t*>(qkv + (size_t)roww * 384 + 128 + chb + g * 8);
    }

    // QK^T into registers: sa[t][nt], t indexes this wave's m-tiles {wv, wv+4}
    f32x4 sa[2][7];
    #pragma unroll
    for (int t = 0; t < 2; ++t)
        #pragma unroll
        for (int nt = 0; nt < 7; ++nt)
            sa[t][nt] = (f32x4){0.f, 0.f, 0.f, 0.f};

    #pragma unroll
    for (int t = 0; t < 2; ++t) {
        int mt = wv + 4 * t;
        if (mt < 7) {
            int roww = rowof(mt * 16 + r);
            short8_t af = *reinterpret_cast<const short8_t*>(qkv + (size_t)roww * 384 + chb + g * 8);
            #pragma unroll
            for (int nt = 0; nt < 7; ++nt)
                sa[t][nt] = __builtin_amdgcn_mfma_f32_16x16x32_bf16(af, kf[nt], sa[t][nt], 0, 0, 0);
        }
    }

    // in-register softmax; rows of frag = g*4+j, cols nt*16+r (16-lane group)
    const float scale = 0.17677669529663687f; // 1/sqrt(32)
    #pragma unroll
    for (int t = 0; t < 2; ++t) {
        int mt = wv + 4 * t;
        if (mt < 7) {
            #pragma unroll
            for (int j = 0; j < 4; ++j) {
                float sv[7];
                float mx = -1e30f;
                #pragma unroll
                for (int nt = 0; nt < 7; ++nt) { sv[nt] = sa[t][nt][j] * scale; mx = fmaxf(mx, sv[nt]); }
                #pragma unroll
                for (int m = 8; m >= 1; m >>= 1) mx = fmaxf(mx, __shfl_xor(mx, m));
                float sum = 0.f;
                #pragma unroll
                for (int nt = 0; nt < 7; ++nt) { sv[nt] = __expf(sv[nt] - mx); sum += sv[nt]; }
                #pragma unroll
                for (int m = 8; m >= 1; m >>= 1) sum += __shfl_xor(sum, m);
                float inv = 1.0f / sum;
                int row = mt * 16 + g * 4 + j;
                #pragma unroll
                for (int nt = 0; nt < 7; ++nt)
                    P[row][nt * 16 + r] = f2bf(sv[nt] * inv);
            }
        }
    }
    __syncthreads();

    // PV + LEPE + store. 14 output frags (7 m-tiles x 2 d-tiles); wave w: w+4t
    #pragma unroll
    for (int t = 0; t < 4; ++t) {
        int idx = wv + 4 * t;
        if (idx < 14) {
            int mt = idx >> 1, nt = idx & 1;
            int m0 = mt * 16, n0 = nt * 16;
            f32x4 acc = {0.f, 0.f, 0.f, 0.f};
            #pragma unroll
            for (int ks = 0; ks < 4; ++ks) {
                short8_t pa, vb;
                if (ks < 3 || g < 2) {
                    int k0 = ks * 32 + g * 8;
                    pa = *reinterpret_cast<const short8_t*>(&P[m0 + r][k0]);
                    vb = *reinterpret_cast<const short8_t*>(&vT[n0 + r][k0]);
                } else {
                    #pragma unroll
                    for (int j = 0; j < 8; ++j) { pa[j] = 0; vb[j] = 0; }
                }
                acc = __builtin_amdgcn_mfma_f32_16x16x32_bf16(pa, vb, acc, 0, 0, 0);
            }
            int d = n0 + r;               // hd index 0..31
            int cl = head * 32 + d;       // depthwise-conv channel 0..63
            float w9[9];
            #pragma unroll
            for (int j = 0; j < 9; ++j) w9[j] = cw[cl * 9 + j];
            float cbias = cb[cl];
            #pragma unroll
            for (int j = 0; j < 4; ++j) {
                int tok = m0 + g * 4 + j;
                float v = acc[j];
                int hs, wsp;
                if (type == 0) { hs = tok >> 1; wsp = tok & 1; }
                else           { hs = (tok >= 56) ? 1 : 0; wsp = tok - hs * 56; }
                float lp = cbias;
                #pragma unroll
                for (int ky = 0; ky < 3; ++ky) {
                    int hh = hs + ky - 1;
                    bool okh = (type == 0) ? (hh >= 0 && hh < 56) : (hh >= 0 && hh < 2);
                    #pragma unroll
                    for (int kx = 0; kx < 3; ++kx) {
                        int wwp = wsp + kx - 1;
                        bool okw = (type == 0) ? (wwp >= 0 && wwp < 2) : (wwp >= 0 && wwp < 56);
                        if (okh && okw) {
                            int tt = (type == 0) ? (hh * 2 + wwp) : (hh * 56 + wwp);
                            lp += w9[ky * 3 + kx] * bf2f(vT[d][tt]);
                        }
                    }
                }
                v += lp;
                int roww = rowof(tok);
                attout[(size_t)roww * 128 + chb + d] = f2bf(v);
            }
        }
    }
}

extern "C" void kernel_launch(void* const* d_in, const int* in_sizes, int n_in,
                              void* d_out, int out_size, void* d_ws, size_t ws_size,
                              hipStream_t stream) {
    const float* x      = (const float*)d_in[0];
    const float* n1g    = (const float*)d_in[1];
    const float* n1b    = (const float*)d_in[2];
    const float* qkv_w  = (const float*)d_in[3];
    const float* proj_w = (const float*)d_in[4];
    const float* proj_b = (const float*)d_in[5];
    const float* cw0    = (const float*)d_in[6];
    const float* cb0    = (const float*)d_in[7];
    const float* cw1    = (const float*)d_in[8];
    const float* cb1    = (const float*)d_in[9];
    const float* n2g    = (const float*)d_in[10];
    const float* n2b    = (const float*)d_in[11];
    const float* fc1_w  = (const float*)d_in[12];
    const float* fc1_b  = (const float*)d_in[13];
    const float* fc2_w  = (const float*)d_in[14];
    const float* fc2_b  = (const float*)d_in[15];
    float* out = (float*)d_out;
    char* ws = (char*)d_ws;

    // workspace layout (bytes)
    short* img   = (short*)(ws + 0);            // [100352][128] bf16; later y2 (LN2 out)
    short* qkv   = (short*)(ws + 25690112);     // [100352][384] bf16
    short* att   = (short*)(ws + 102760448);    // [100352][128] bf16
    float* xres  = (float*)(ws + 128450560);    // [100352][128] f32
    short* wT    = (short*)(ws + 179830784);    // all weights bf16 [N][K]
    short* wqkvT  = wT;
    short* wprojT = wT + 49152;
    short* wfc1T  = wT + 65536;
    short* wfc2T  = wT + 131072;
    short* y2     = img;   // LN2 output aliases img (dead after qkv GEMM)

    prep_weights<<<768, 256, 0, stream>>>(qkv_w, proj_w, fc1_w, fc2_w, wT);
    ln_kernel<<<25088, 256, 0, stream>>>(x, n1g, n1b, img);
    gemm128<0><<<dim3(784, 3), 256, 0, stream>>>(img, wqkvT, nullptr, nullptr, nullptr, nullptr,
                                                 qkv, nullptr, 384);
    attn_kernel<<<dim3(896, 2, 2), 256, 0, stream>>>(qkv, cw0, cb0, cw1, cb1, att);
    gemm128<1><<<dim3(784, 1), 256, 0, stream>>>(att, wprojT, proj_b, x, n2g, n2b,
                                                 y2, xres, 128);
    mlp_kernel<<<1568, 256, 0, stream>>>(y2, wfc1T, fc1_b, wfc2T, fc2_b, xres, out);
}